// Round 13
// baseline (7293.182 us; speedup 1.0000x reference)
//
#include <hip/hip_runtime.h>
#include <math.h>

// ---------------- dims ----------------
#define B_    4
#define N_    512
#define D_    256
#define H_    8
#define DH_   32
#define M_    110
#define MP_   112           // padded M (pads are exact zeros)
#define FF_   1024
#define HID_  256
#define ROWS_ 2048          // B*N
#define CHUNK 32
#define NCH   16            // N_/CHUNK

// ---------------- ws layout (float offsets) ----------------
#define OFF_H      0u
#define OFF_Y      524288u
#define OFF_Q      1048576u
#define OFF_K      1572864u
#define OFF_V      2097152u
#define OFF_O      2621440u
#define OFF_FF     3145728u   // FF hidden; reused as BLa/BLb in LSTM phase
#define OFF_QP     5242880u   // reused as gi (4194304 spans QP+KP) in LSTM phase
#define OFF_KP     7077888u
#define OFF_S      8912896u
#define OFF_MB     9437184u   // LSTM h-mailboxes, 3 layers x [2][512][4][256]
#define OFF_P      10747904u  // (dead: cpref removed)
#define OFF_KSUM   12582912u
#define OFF_PK     12640256u  // (dead)
#define OFF_DIAG   12697600u
#define OFF_KMAX   12713984u  // 256 uints: 8 layers x 32
// END = 12718208 floats = ~48.5 MiB

#define SCALE_X 0.42044820762685725f   // 32^-0.25
#define SCALE_M 0.09534625892455924f   // 110^-0.5

__device__ __forceinline__ float sigmoidf_(float x){ return 1.0f/(1.0f+expf(-x)); }
__device__ __forceinline__ float geluf_(float x){ return 0.5f*x*(1.0f+erff(x*0.70710678118654752f)); }
__device__ __forceinline__ unsigned encf_(float x){ unsigned u=__float_as_uint(x); return (u&0x80000000u)?~u:(u|0x80000000u); }
__device__ __forceinline__ float decf_(unsigned u){ return (u&0x80000000u)?__uint_as_float(u&0x7fffffffu):__uint_as_float(~u); }

typedef unsigned u32x4_ __attribute__((ext_vector_type(4)));

// Coherent 16B poll load (MALL / device scope) — the proven r9 protocol.
__device__ __forceinline__ u32x4_ ld4_far_(const unsigned* p){
  u32x4_ v;
  asm volatile("global_load_dwordx4 %0, %1, off sc0 sc1\n\ts_waitcnt vmcnt(0)"
               : "=v"(v) : "v"(p));
  return v;
}

// ---------------- small-tile fp32 GEMM (32x32, 2 blocks/CU): C = act(A@W^T + b1 + b2) + R ----------------
// Per-output ascending-k accumulation: bitwise-identical to all other tilings.
__global__ __launch_bounds__(256) void gemms_k(
    const float* __restrict__ A, const float* __restrict__ W,
    const float* __restrict__ b1, const float* __restrict__ b2,
    const float* __restrict__ R, float* __restrict__ C,
    int M, int N, int K, int act)
{
  __shared__ float As[16][36];
  __shared__ float Ws[16][36];
  const int tid = threadIdx.x;
  const int tx = tid & 15, ty = tid >> 4;
  const int i0 = blockIdx.y * 32, j0 = blockIdx.x * 32;
  const int lr = tid >> 3, lc = (tid & 7) << 1;
  const float* pA = A + (size_t)(i0 + lr) * K + lc;
  const float* pW = W + (size_t)(j0 + lr) * K + lc;
  float a00=0.f, a01=0.f, a10=0.f, a11=0.f;
  float2 a2 = *(const float2*)pA;
  float2 w2 = *(const float2*)pW;
  for (int k0 = 0; k0 < K; k0 += 16) {
    __syncthreads();
    As[lc+0][lr]=a2.x; As[lc+1][lr]=a2.y;
    Ws[lc+0][lr]=w2.x; Ws[lc+1][lr]=w2.y;
    float2 a2n = a2, w2n = w2;
    if (k0 + 16 < K) {
      a2n = *(const float2*)(pA + k0 + 16);
      w2n = *(const float2*)(pW + k0 + 16);
    }
    __syncthreads();
    #pragma unroll
    for (int kk = 0; kk < 16; kk++) {
      float2 av = *(const float2*)&As[kk][ty*2];
      float2 wv = *(const float2*)&Ws[kk][tx*2];
      a00 += av.x*wv.x; a01 += av.x*wv.y;
      a10 += av.y*wv.x; a11 += av.y*wv.y;
    }
    a2 = a2n; w2 = w2n;
  }
  float accv[2][2] = {{a00,a01},{a10,a11}};
  #pragma unroll
  for (int ii = 0; ii < 2; ii++) {
    int gi_ = i0 + ty*2 + ii;
    #pragma unroll
    for (int jj = 0; jj < 2; jj++) {
      int gj = j0 + tx*2 + jj;
      float v = accv[ii][jj];
      if (b1) v += b1[gj];
      if (b2) v += b2[gj];
      if (act) v = geluf_(v);
      if (R) v += R[(size_t)gi_ * N + gj];
      C[(size_t)gi_ * N + gj] = v;
    }
  }
}

// ---------------- fused QKV GEMM (32x32 tiles, 3 blocks/CU) ----------------
__global__ __launch_bounds__(256) void gemm3_k(
    const float* __restrict__ A,
    const float* __restrict__ W0, const float* __restrict__ W1, const float* __restrict__ W2,
    const float* __restrict__ c0_, const float* __restrict__ c1_, const float* __restrict__ c2_,
    float* __restrict__ O0, float* __restrict__ O1, float* __restrict__ O2)
{
  const int which = blockIdx.x >> 3;
  const float* W  = which == 0 ? W0 : which == 1 ? W1 : W2;
  const float* bb = which == 0 ? c0_ : which == 1 ? c1_ : c2_;
  float* C        = which == 0 ? O0 : which == 1 ? O1 : O2;
  __shared__ float As[16][36];
  __shared__ float Ws[16][36];
  const int tid = threadIdx.x;
  const int tx = tid & 15, ty = tid >> 4;
  const int i0 = blockIdx.y * 32, j0 = (blockIdx.x & 7) * 32;
  const int lr = tid >> 3, lc = (tid & 7) << 1;
  const float* pA = A + (size_t)(i0 + lr) * 256 + lc;
  const float* pW = W + (size_t)(j0 + lr) * 256 + lc;
  float a00=0.f, a01=0.f, a10=0.f, a11=0.f;
  float2 a2 = *(const float2*)pA;
  float2 w2 = *(const float2*)pW;
  for (int k0 = 0; k0 < 256; k0 += 16) {
    __syncthreads();
    As[lc+0][lr]=a2.x; As[lc+1][lr]=a2.y;
    Ws[lc+0][lr]=w2.x; Ws[lc+1][lr]=w2.y;
    float2 a2n = a2, w2n = w2;
    if (k0 + 16 < 256) {
      a2n = *(const float2*)(pA + k0 + 16);
      w2n = *(const float2*)(pW + k0 + 16);
    }
    __syncthreads();
    #pragma unroll
    for (int kk = 0; kk < 16; kk++) {
      float2 av = *(const float2*)&As[kk][ty*2];
      float2 wv = *(const float2*)&Ws[kk][tx*2];
      a00 += av.x*wv.x; a01 += av.x*wv.y;
      a10 += av.y*wv.x; a11 += av.y*wv.y;
    }
    a2 = a2n; w2 = w2n;
  }
  float accv[2][2] = {{a00,a01},{a10,a11}};
  #pragma unroll
  for (int ii = 0; ii < 2; ii++) {
    int gi_ = i0 + ty*2 + ii;
    #pragma unroll
    for (int jj = 0; jj < 2; jj++) {
      int gj = j0 + tx*2 + jj;
      C[(size_t)gi_ * 256 + gj] = accv[ii][jj] + bb[gj];
    }
  }
}

// ---------------- generic fp32 GEMM (64x64 tile, reg-prefetched): used for FF1 (2 blocks/CU) ----------------
__global__ __launch_bounds__(256) void gemm_k(
    const float* __restrict__ A, const float* __restrict__ W,
    const float* __restrict__ b1, const float* __restrict__ b2,
    const float* __restrict__ R, float* __restrict__ C,
    int M, int N, int K, int act)
{
  __shared__ float As[16][72];
  __shared__ float Ws[16][72];
  const int tid = threadIdx.x;
  const int tx = tid & 15, ty = tid >> 4;
  const int i0 = blockIdx.y * 64, j0 = blockIdx.x * 64;
  const int lr = tid >> 2, lc = (tid & 3) << 2;
  const float* pA = A + (size_t)(i0 + lr) * K + lc;
  const float* pW = W + (size_t)(j0 + lr) * K + lc;
  float acc[4][4] = {};
  float4 a4 = *(const float4*)pA;
  float4 w4 = *(const float4*)pW;
  for (int k0 = 0; k0 < K; k0 += 16) {
    __syncthreads();
    As[lc+0][lr]=a4.x; As[lc+1][lr]=a4.y; As[lc+2][lr]=a4.z; As[lc+3][lr]=a4.w;
    Ws[lc+0][lr]=w4.x; Ws[lc+1][lr]=w4.y; Ws[lc+2][lr]=w4.z; Ws[lc+3][lr]=w4.w;
    float4 a4n = a4, w4n = w4;
    if (k0 + 16 < K) {
      a4n = *(const float4*)(pA + k0 + 16);
      w4n = *(const float4*)(pW + k0 + 16);
    }
    __syncthreads();
    #pragma unroll
    for (int kk = 0; kk < 16; kk++) {
      float4 av = *(const float4*)&As[kk][ty*4];
      float4 wv = *(const float4*)&Ws[kk][tx*4];
      acc[0][0] += av.x*wv.x; acc[0][1] += av.x*wv.y; acc[0][2] += av.x*wv.z; acc[0][3] += av.x*wv.w;
      acc[1][0] += av.y*wv.x; acc[1][1] += av.y*wv.y; acc[1][2] += av.y*wv.z; acc[1][3] += av.y*wv.w;
      acc[2][0] += av.z*wv.x; acc[2][1] += av.z*wv.y; acc[2][2] += av.z*wv.z; acc[2][3] += av.z*wv.w;
      acc[3][0] += av.w*wv.x; acc[3][1] += av.w*wv.y; acc[3][2] += av.w*wv.z; acc[3][3] += av.w*wv.w;
    }
    a4 = a4n; w4 = w4n;
  }
  #pragma unroll
  for (int ii = 0; ii < 4; ii++) {
    int gi_ = i0 + ty*4 + ii;
    #pragma unroll
    for (int jj = 0; jj < 4; jj++) {
      int gj = j0 + tx*4 + jj;
      float v = acc[ii][jj];
      if (b1) v += b1[gj];
      if (b2) v += b2[gj];
      if (act) v = geluf_(v);
      if (R) v += R[(size_t)gi_ * N + gj];
      C[(size_t)gi_ * N + gj] = v;
    }
  }
}

// ---------------- fused dual-dir LSTM input GEMM (64x64, 4 blocks/CU, reg-prefetched) ----------------
__global__ __launch_bounds__(256) void gemmgi_k(
    const float* __restrict__ A, const float* __restrict__ W, const float* __restrict__ bvec,
    float* __restrict__ C, int K, int wGap, int bGap)
{
  const int dir = blockIdx.x >> 4;
  const float* Wd = W + (size_t)dir * wGap;
  const float* b1 = bvec + (size_t)dir * bGap;
  const float* b2 = b1 + 1024;
  float* Cd = C + (size_t)dir * 2097152;
  __shared__ float As[16][72];
  __shared__ float Ws[16][72];
  const int tid = threadIdx.x;
  const int tx = tid & 15, ty = tid >> 4;
  const int i0 = blockIdx.y * 64, j0 = (blockIdx.x & 15) * 64;
  const int lr = tid >> 2, lc = (tid & 3) << 2;
  const float* pA = A + (size_t)(i0 + lr) * K + lc;
  const float* pW = Wd + (size_t)(j0 + lr) * K + lc;
  float acc[4][4] = {};
  float4 a4 = *(const float4*)pA;
  float4 w4 = *(const float4*)pW;
  for (int k0 = 0; k0 < K; k0 += 16) {
    __syncthreads();
    As[lc+0][lr]=a4.x; As[lc+1][lr]=a4.y; As[lc+2][lr]=a4.z; As[lc+3][lr]=a4.w;
    Ws[lc+0][lr]=w4.x; Ws[lc+1][lr]=w4.y; Ws[lc+2][lr]=w4.z; Ws[lc+3][lr]=w4.w;
    float4 a4n = a4, w4n = w4;
    if (k0 + 16 < K) {
      a4n = *(const float4*)(pA + k0 + 16);
      w4n = *(const float4*)(pW + k0 + 16);
    }
    __syncthreads();
    #pragma unroll
    for (int kk = 0; kk < 16; kk++) {
      float4 av = *(const float4*)&As[kk][ty*4];
      float4 wv = *(const float4*)&Ws[kk][tx*4];
      acc[0][0] += av.x*wv.x; acc[0][1] += av.x*wv.y; acc[0][2] += av.x*wv.z; acc[0][3] += av.x*wv.w;
      acc[1][0] += av.y*wv.x; acc[1][1] += av.y*wv.y; acc[1][2] += av.y*wv.z; acc[1][3] += av.y*wv.w;
      acc[2][0] += av.z*wv.x; acc[2][1] += av.z*wv.y; acc[2][2] += av.z*wv.z; acc[2][3] += av.z*wv.w;
      acc[3][0] += av.w*wv.x; acc[3][1] += av.w*wv.y; acc[3][2] += av.w*wv.z; acc[3][3] += av.w*wv.w;
    }
    a4 = a4n; w4 = w4n;
  }
  #pragma unroll
  for (int ii = 0; ii < 4; ii++) {
    int gi_ = i0 + ty*4 + ii;
    #pragma unroll
    for (int jj = 0; jj < 4; jj++) {
      int gj = j0 + tx*4 + jj;
      Cd[(size_t)gi_ * 1024 + gj] = acc[ii][jj] + b1[gj] + b2[gj];
    }
  }
}

// ---------------- LayerNorm over 256 channels ----------------
__global__ __launch_bounds__(256) void ln_k(const float* __restrict__ x, const float* __restrict__ w,
                                            const float* __restrict__ b, float* __restrict__ y)
{
  const int row = blockIdx.x, t = threadIdx.x;
  float v = x[(size_t)row * 256 + t];
  float s = v;
  #pragma unroll
  for (int o = 32; o >= 1; o >>= 1) s += __shfl_xor(s, o, 64);
  __shared__ float w1_[4], w2_[4];
  const int wid = t >> 6, lane = t & 63;
  if (lane == 0) w1_[wid] = s;
  __syncthreads();
  float mu = (w1_[0] + w1_[1] + w1_[2] + w1_[3]) * (1.0f/256.0f);
  float d = v - mu;
  float s2 = d * d;
  #pragma unroll
  for (int o = 32; o >= 1; o >>= 1) s2 += __shfl_xor(s2, o, 64);
  if (lane == 0) w2_[wid] = s2;
  __syncthreads();
  float var = (w2_[0] + w2_[1] + w2_[2] + w2_[3]) * (1.0f/256.0f);
  y[(size_t)row * 256 + t] = d * (1.0f / sqrtf(var + 1e-5f)) * w[t] + b[t];
}

// ---------------- FAVOR+ features, fused q|k ----------------
__global__ __launch_bounds__(256) void feat_k(const float* __restrict__ q, const float* __restrict__ kk,
                                              const float* __restrict__ proj,
                                              float* __restrict__ qp, float* __restrict__ kpraw,
                                              float* __restrict__ diagb, unsigned* __restrict__ kmax)
{
  const int isq = (blockIdx.x < 4096);
  const int bx = isq ? blockIdx.x : (blockIdx.x - 4096);
  const int wid = threadIdx.x >> 6, lane = threadIdx.x & 63;
  const int p = bx * 4 + wid;
  const int bh = p >> 9, n = p & 511;
  const int b = bh >> 3, h = bh & 7;
  __shared__ float xs[4][32];
  const float* xrow = (isq ? q : kk) + ((size_t)(b * N_ + n)) * D_ + h * DH_;
  if (lane < 32) xs[wid][lane] = xrow[lane] * SCALE_X;
  __syncthreads();
  float diag = 0.f;
  #pragma unroll
  for (int d = 0; d < 32; d++) { float xv = xs[wid][d]; diag += xv * xv; }
  diag *= 0.5f;
  const int m0 = lane, m1 = 64 + lane;
  float dd0 = 0.f, dd1 = -INFINITY;
  #pragma unroll
  for (int d = 0; d < 32; d++) dd0 += xs[wid][d] * proj[m0 * 32 + d];
  if (m1 < M_) {
    float a = 0.f;
    #pragma unroll
    for (int d = 0; d < 32; d++) a += xs[wid][d] * proj[m1 * 32 + d];
    dd1 = a;
  }
  float mx = fmaxf(dd0, dd1);
  #pragma unroll
  for (int o = 32; o >= 1; o >>= 1) mx = fmaxf(mx, __shfl_xor(mx, o, 64));
  if (isq) {
    float* out = qp + (size_t)p * MP_;
    out[m0] = SCALE_M * (expf(dd0 - diag - mx) + 1e-4f);
    if (m1 < M_)        out[m1] = SCALE_M * (expf(dd1 - diag - mx) + 1e-4f);
    else if (m1 < MP_)  out[m1] = 0.f;
  } else {
    float* out = kpraw + (size_t)p * MP_;
    out[m0] = dd0;
    if (m1 < M_) out[m1] = dd1;
    if (lane == 0) { diagb[p] = diag; atomicMax(kmax + bh, encf_(mx)); }
  }
}

// ---------------- chunked linear attention: per-chunk K-state sums (finalize fused) ----------------
__global__ __launch_bounds__(256) void csum_k(const float* __restrict__ kp, const float* __restrict__ v,
                                              const float* __restrict__ diagb, const unsigned* __restrict__ kmax,
                                              float* __restrict__ S, float* __restrict__ ksum)
{
  const int bh = blockIdx.x >> 4, c = blockIdx.x & 15;
  const int b = bh >> 3, h = bh & 7;
  __shared__ float kpc[CHUNK * MP_];
  __shared__ float vc[CHUNK][DH_];
  const float* kpbase = kp + ((size_t)bh * N_ + c * CHUNK) * MP_;
  const float kmx = decf_(kmax[bh]);
  const int r0 = bh * N_ + c * CHUNK;
  for (int f = threadIdx.x; f < CHUNK * MP_; f += 256) {
    int i = f / MP_, m = f - i * MP_;
    float raw = kpbase[f];
    float val = 0.f;
    if (m < M_) val = SCALE_M * (expf(raw - diagb[r0 + i] - kmx) + 1e-4f);
    kpc[f] = val;
  }
  for (int f = threadIdx.x; f < CHUNK * DH_; f += 256) {
    int i = f >> 5, d = f & 31;
    vc[i][d] = v[((size_t)(b * N_ + c * CHUNK + i)) * D_ + h * DH_ + d];
  }
  __syncthreads();
  const int d = threadIdx.x & 31, mg = threadIdx.x >> 5;
  float Sa[14] = {};
  for (int i = 0; i < CHUNK; i++) {
    float vv = vc[i][d];
    #pragma unroll
    for (int j = 0; j < 14; j++) Sa[j] += kpc[i * MP_ + mg * 14 + j] * vv;
  }
  float* Sout = S + (((size_t)blockIdx.x) * MP_ + mg * 14) * DH_ + d;
  #pragma unroll
  for (int j = 0; j < 14; j++) Sout[(size_t)j * DH_] = Sa[j];
  if (threadIdx.x < MP_) {
    float s = 0.f;
    for (int i = 0; i < CHUNK; i++) s += kpc[i * MP_ + threadIdx.x];
    ksum[(size_t)blockIdx.x * MP_ + threadIdx.x] = s;
  }
}

// ---------------- intra-chunk causal attention + combine (k finalize + chunk-prefix fused) ----------------
// P/pk are computed in-block by summing S/ksum over chunks cc<c in ascending order — the exact
// order cpref_k used, so results are bitwise identical and cpref_k is eliminated.
__global__ __launch_bounds__(256, 1) void attn_k(const float* __restrict__ qp, const float* __restrict__ kp,
                                                 const float* __restrict__ v,
                                                 const float* __restrict__ S, const float* __restrict__ ksum,
                                                 const float* __restrict__ diagb, const unsigned* __restrict__ kmax,
                                                 float* __restrict__ o)
{
  const int bh = blockIdx.x >> 4, c = blockIdx.x & 15;
  const int b = bh >> 3, h = bh & 7;
  __shared__ float qpc[CHUNK * 113];
  __shared__ float kpc[CHUNK * 113];
  __shared__ float vc[CHUNK][DH_];
  __shared__ float Pl[MP_ * DH_];
  __shared__ float pkl[MP_];
  __shared__ float Al[CHUNK * 33];
  __shared__ float den[CHUNK];
  const int t = threadIdx.x;
  const float* qbase = qp + ((size_t)bh * N_ + c * CHUNK) * MP_;
  const float* kbase = kp + ((size_t)bh * N_ + c * CHUNK) * MP_;
  const float kmx = decf_(kmax[bh]);
  const int r0 = bh * N_ + c * CHUNK;
  for (int f = t; f < CHUNK * MP_; f += 256) {
    int i = f / MP_, m = f - i * MP_;
    qpc[i * 113 + m] = qbase[f];
    float raw = kbase[f];
    float val = 0.f;
    if (m < M_) val = SCALE_M * (expf(raw - diagb[r0 + i] - kmx) + 1e-4f);
    kpc[i * 113 + m] = val;
  }
  for (int f = t; f < CHUNK * DH_; f += 256) {
    int i = f >> 5, d = f & 31;
    vc[i][d] = v[((size_t)(b * N_ + c * CHUNK + i)) * D_ + h * DH_ + d];
  }
  // chunk-prefix: ascending cc (matches old cpref running-sum order exactly)
  {
    const float* Sb = S + (size_t)(bh * NCH) * MP_ * DH_;
    for (int f = t; f < MP_ * DH_; f += 256) {
      float accp = 0.f;
      for (int cc = 0; cc < c; cc++) accp += Sb[(size_t)cc * MP_ * DH_ + f];
      Pl[f] = accp;
    }
    if (t < MP_) {
      const float* Kb2 = ksum + (size_t)(bh * NCH) * MP_;
      float r = 0.f;
      for (int cc = 0; cc < c; cc++) r += Kb2[(size_t)cc * MP_ + t];
      pkl[t] = r;
    }
  }
  __syncthreads();
  { // causal score tile 2x2 per thread
    const int ti = t >> 4, tj = t & 15;
    float a00 = 0.f, a01 = 0.f, a10 = 0.f, a11 = 0.f;
    for (int m = 0; m < MP_; m++) {
      float q0 = qpc[(ti*2+0)*113 + m], q1 = qpc[(ti*2+1)*113 + m];
      float k0 = kpc[(tj*2+0)*113 + m], k1 = kpc[(tj*2+1)*113 + m];
      a00 += q0*k0; a01 += q0*k1; a10 += q1*k0; a11 += q1*k1;
    }
    const int i0_ = ti*2, j0_ = tj*2;
    Al[(i0_  )*33 + j0_  ] = (j0_   <= i0_  ) ? a00 : 0.f;
    Al[(i0_  )*33 + j0_+1] = (j0_+1 <= i0_  ) ? a01 : 0.f;
    Al[(i0_+1)*33 + j0_  ] = (j0_   <= i0_+1) ? a10 : 0.f;
    Al[(i0_+1)*33 + j0_+1] = (j0_+1 <= i0_+1) ? a11 : 0.f;
  }
  __syncthreads();
  if (t < CHUNK) {
    const int i = t; float s = 0.f;
    for (int m = 0; m < MP_; m++) s += qpc[i*113 + m] * pkl[m];
    for (int j = 0; j <= i; j++) s += Al[i*33 + j];
    den[i] = 1.0f / (s + 1e-6f);
  }
  __syncthreads();
  {
    const int d = t & 31, ig = t >> 5;
    float Pd[MP_];
    #pragma unroll
    for (int m = 0; m < MP_; m++) Pd[m] = Pl[m * DH_ + d];
    float vd[CHUNK];
    #pragma unroll
    for (int j = 0; j < CHUNK; j++) vd[j] = vc[j][d];
    for (int r = 0; r < 4; r++) {
      const int i = ig * 4 + r;
      float acc = 0.f;
      #pragma unroll
      for (int m = 0; m < MP_; m++) acc += qpc[i*113 + m] * Pd[m];
      #pragma unroll
      for (int j = 0; j < CHUNK; j++) acc += Al[i*33 + j] * vd[j];
      o[((size_t)(b * N_ + c * CHUNK + i)) * D_ + h * DH_ + d] = acc * den[i];
    }
  }
}

// ---------------- BiLSTM recurrence: 32 worker blocks (16/dir) — r9 proven protocol (frozen) ----------------
__global__ __launch_bounds__(256, 1) void rec_k(
    const float* __restrict__ gi, const float* __restrict__ whh,
    float* __restrict__ hs, float* __restrict__ hx)
{
  const int bid = blockIdx.x;
  if ((bid & 7) > 1) return;
  const int dir = bid & 7;
  const int s = bid >> 3;
  if (s >= 16) return;
  const int t = threadIdx.x;

  __shared__ __align__(16) float h_sh[4][256];   // [b][k]
  __shared__ __align__(16) float red[64 * 33];   // [rho][b*8+kq]

  __builtin_amdgcn_fence(__ATOMIC_ACQUIRE, "agent");

  const float* giD = gi + (size_t)dir * 2097152;
  const float* whD = whh + (size_t)dir * 262144;
  float* hxD = hx + (size_t)dir * 524288;        // [512][4][256]

  const int rg = t & 31, kq = t >> 5;
  float4 w4[2][8];
  #pragma unroll
  for (int rr = 0; rr < 2; rr++) {
    const int rho = rg * 2 + rr;
    const int grow = (rho >> 4) * 256 + s * 16 + (rho & 15);   // gate-major global row
    const float4* src = (const float4*)(whD + (size_t)grow * 256 + kq * 32);
    #pragma unroll
    for (int q = 0; q < 8; q++) w4[rr][q] = src[q];
  }

  const int j = t & 15, bb = t >> 4;
  const float* pgi0 = giD + (size_t)bb * 524288 + (size_t)(s * 16 + j);

  ((float4*)h_sh)[t] = make_float4(0.f, 0.f, 0.f, 0.f);
  float c0 = 0.f;
  __syncthreads();

  int n = dir ? 511 : 0;
  float gnext[4];
  if (t < 64) {
    #pragma unroll
    for (int g = 0; g < 4; g++) gnext[g] = pgi0[(size_t)n * 1024 + g * 256];
  }

  for (int step = 0; step < 512; step++) {
    const int n2 = dir ? (510 - step) : (step + 1);
    float gcur[4];
    if (t < 64) {
      #pragma unroll
      for (int g = 0; g < 4; g++) gcur[g] = gnext[g];
      if (step < 511) {
        #pragma unroll
        for (int g = 0; g < 4; g++) gnext[g] = pgi0[(size_t)n2 * 1024 + g * 256];
      }
    }

    float acc[2][4] = {};
    #pragma unroll
    for (int q = 0; q < 8; q++) {
      float4 h0 = *(const float4*)&h_sh[0][kq * 32 + q * 4];
      float4 h1 = *(const float4*)&h_sh[1][kq * 32 + q * 4];
      float4 h2 = *(const float4*)&h_sh[2][kq * 32 + q * 4];
      float4 h3 = *(const float4*)&h_sh[3][kq * 32 + q * 4];
      #pragma unroll
      for (int rr = 0; rr < 2; rr++) {
        float4 w = w4[rr][q];
        acc[rr][0] += w.x*h0.x + w.y*h0.y + w.z*h0.z + w.w*h0.w;
        acc[rr][1] += w.x*h1.x + w.y*h1.y + w.z*h1.z + w.w*h1.w;
        acc[rr][2] += w.x*h2.x + w.y*h2.y + w.z*h2.z + w.w*h2.w;
        acc[rr][3] += w.x*h3.x + w.y*h3.y + w.z*h3.z + w.w*h3.w;
      }
    }
    #pragma unroll
    for (int rr = 0; rr < 2; rr++)
      #pragma unroll
      for (int b = 0; b < 4; b++)
        red[(rg * 2 + rr) * 33 + b * 8 + kq] = acc[rr][b];
    __syncthreads();                                     // [A]

    if (t < 64) {
      float pre[4];
      #pragma unroll
      for (int g = 0; g < 4; g++) {
        const float* rp = &red[(g * 16 + j) * 33 + bb * 8];
        float sum = gcur[g];
        #pragma unroll
        for (int q = 0; q < 8; q++) sum += rp[q];
        pre[g] = sum;
      }
      c0 = sigmoidf_(pre[1]) * c0 + sigmoidf_(pre[0]) * tanhf(pre[2]);
      const float hv = sigmoidf_(pre[3]) * tanhf(c0);
      if (step < 511) {
        __hip_atomic_store(hxD + (size_t)step * 1024 + bb * 256 + s * 16 + j, hv,
                           __ATOMIC_RELAXED, __HIP_MEMORY_SCOPE_AGENT);
      }
      hs[(size_t)(bb * 512 + n) * 512 + dir * 256 + s * 16 + j] = hv;
    }

    if (step < 511) {
      const unsigned* pp = (const unsigned*)(hxD + (size_t)step * 1024) + t * 4;
      u32x4_ v = ld4_far_(pp);
      while (v.x == 0xFFFFFFFFu || v.y == 0xFFFFFFFFu ||
             v.z == 0xFFFFFFFFu || v.w == 0xFFFFFFFFu) {
        v = ld4_far_(pp);
      }
      float4 hv4;
      hv4.x = __uint_as_float(v.x); hv4.y = __uint_as_float(v.y);
      hv4.z = __uint_as_float(v.z); hv4.w = __uint_as_float(v.w);
      ((float4*)h_sh)[t] = hv4;
      __syncthreads();                                   // [C]
    }
    n = n2;
  }
}

// ---------------- final head ----------------
__global__ __launch_bounds__(256) void fc_k(const float* __restrict__ hs, const float* __restrict__ fw,
                                            const float* __restrict__ fb, float* __restrict__ out)
{
  const int t = threadIdx.x;
  float p[4] = {};
  for (int j = t; j < 512; j += 256) {
    const float w = fw[j];
    #pragma unroll
    for (int b = 0; b < 4; b++) p[b] += hs[(size_t)(b * 512 + 511) * 512 + j] * w;
  }
  #pragma unroll
  for (int b = 0; b < 4; b++)
    #pragma unroll
    for (int o = 32; o >= 1; o >>= 1) p[b] += __shfl_xor(p[b], o, 64);
  __shared__ float r4[4][4];
  const int wid = t >> 6, lane = t & 63;
  if (lane == 0) {
    #pragma unroll
    for (int b = 0; b < 4; b++) r4[b][wid] = p[b];
  }
  __syncthreads();
  if (t == 0) {
    #pragma unroll
    for (int b = 0; b < 4; b++) out[b] = r4[b][0] + r4[b][1] + r4[b][2] + r4[b][3] + fb[0];
  }
}

// ---------------- host ----------------
extern "C" void kernel_launch(void* const* d_in, const int* in_sizes, int n_in,
                              void* d_out, int out_size, void* d_ws, size_t ws_size,
                              hipStream_t stream) {
  (void)in_sizes; (void)n_in; (void)out_size; (void)ws_size;
  const float* x     = (const float*)d_in[0];
  const float* Win_w = (const float*)d_in[1];
  const float* Win_b = (const float*)d_in[2];
  const float* ln1w  = (const float*)d_in[3];
  const float* ln1b  = (const float*)d_in[4];
  const float* Wq    = (const float*)d_in[5];
  const float* bq    = (const float*)d_in[6];
  const float* Wk    = (const float*)d_in[7];
  const float* bk    = (const float*)d_in[8];
  const float* Wv    = (const float*)d_in[9];
  const float* bv    = (const float*)d_in[10];
  const float* Wo    = (const float*)d_in[11];
  const float* bo    = (const float*)d_in[12];
  const float* proj  = (const float*)d_in[13];
  const float* ln2w  = (const float*)d_in[14];
  const float* ln2b  = (const float*)d_in[15];
  const float* Wff1  = (const float*)d_in[16];
  const float* bff1  = (const float*)d_in[17];
  const float* Wff2  = (const float*)d_in[18];
  const float* bff2  = (const float*)d_in[19];
  const float* Wih0  = (const float*)d_in[20];
  const float* Whh0  = (const float*)d_in[21];
  const float* b0    = (const float*)d_in[22];
  const float* Wih12 = (const float*)d_in[23];
  const float* Whh12 = (const float*)d_in[24];
  const float* b12   = (const float*)d_in[25];
  const float* fcw   = (const float*)d_in[26];
  const float* fcb   = (const float*)d_in[27];

  float* ws = (float*)d_ws;
  float* H   = ws + OFF_H;
  float* Y   = ws + OFF_Y;
  float* Q   = ws + OFF_Q;
  float* Kb  = ws + OFF_K;
  float* V   = ws + OFF_V;
  float* O   = ws + OFF_O;
  float* FFb = ws + OFF_FF;
  float* QP  = ws + OFF_QP;
  float* KP  = ws + OFF_KP;
  float* S   = ws + OFF_S;
  float* KS  = ws + OFF_KSUM;
  float* DG  = ws + OFF_DIAG;
  unsigned* KMAX = (unsigned*)(ws + OFF_KMAX);   // 8 layers x 32 slots
  float* GI  = ws + OFF_QP;
  float* MA  = ws + OFF_MB;
  float* BLa = ws + OFF_FF;
  float* BLb = ws + OFF_FF + 1048576;

  const dim3 blk(256);
  const dim3 gs256(8, 64);             // 32x32 tiles, N=256 (512 blocks)
  const dim3 g3(24, 64);               // fused QKV 32x32 tiles (1536 blocks)
  const dim3 g1024(16, 32);            // 64x64 tiles, N=1024 (512 blocks) - FF1
  const dim3 ggi(32, 32);              // 64x64 dual-dir gi (1024 blocks)

  // zero all 8 layers' kmax slots once
  (void)hipMemsetAsync(KMAX, 0, 256 * sizeof(unsigned), stream);

  // input projection
  gemms_k<<<gs256, blk, 0, stream>>>(x, Win_w, Win_b, nullptr, nullptr, H, ROWS_, 256, 128, 0);

  for (int l = 0; l < 8; l++) {
    const float* prj = proj + (size_t)l * 3520;
    unsigned* kmx = KMAX + l * 32;
    ln_k<<<ROWS_, blk, 0, stream>>>(H, ln1w + l*256, ln1b + l*256, Y);
    gemm3_k<<<g3, blk, 0, stream>>>(Y, Wq + (size_t)l*65536, Wk + (size_t)l*65536, Wv + (size_t)l*65536,
                                    bq + l*256, bk + l*256, bv + l*256, Q, Kb, V);
    feat_k<<<8192, blk, 0, stream>>>(Q, Kb, prj, QP, KP, DG, kmx);
    csum_k<<<512, blk, 0, stream>>>(KP, V, DG, kmx, S, KS);
    attn_k<<<512, blk, 0, stream>>>(QP, KP, V, S, KS, DG, kmx, O);
    gemms_k<<<gs256, blk, 0, stream>>>(O, Wo + (size_t)l*65536, bo + l*256, nullptr, H, H, ROWS_, 256, 256, 0);
    ln_k<<<ROWS_, blk, 0, stream>>>(H, ln2w + l*256, ln2b + l*256, Y);
    gemm_k<<<g1024, blk, 0, stream>>>(Y, Wff1 + (size_t)l*262144, bff1 + l*1024, nullptr, nullptr, FFb, ROWS_, 1024, 256, 1);
    gemms_k<<<gs256, blk, 0, stream>>>(FFb, Wff2 + (size_t)l*262144, bff2 + l*256, nullptr, H, H, ROWS_, 256, 1024, 0);
  }

  // sentinel-fill all three mailbox regions once
  (void)hipMemsetAsync(MA, 0xFF, 3145728u * sizeof(float), stream);

  // ---- BiLSTM layer 0 (input H, K=256) ----
  gemmgi_k<<<ggi, blk, 0, stream>>>(H, Wih0, b0, GI, 256, 262144, 2048);
  rec_k<<<128, blk, 0, stream>>>(GI, Whh0, BLa, MA);

  // ---- layer 1 (input BLa, K=512) ----
  gemmgi_k<<<ggi, blk, 0, stream>>>(BLa, Wih12, b12, GI, 512, 524288, 2048);
  rec_k<<<128, blk, 0, stream>>>(GI, Whh12, BLb, MA + 1048576);

  // ---- layer 2 (input BLb, K=512) ----
  gemmgi_k<<<ggi, blk, 0, stream>>>(BLb, Wih12 + 1048576, b12 + 4096, GI, 512, 524288, 2048);
  rec_k<<<128, blk, 0, stream>>>(GI, Whh12 + 524288, BLa, MA + 2097152);

  fc_k<<<1, blk, 0, stream>>>(BLa, fcw, fcb, (float*)d_out);
}

// Round 14
// 6568.954 us; speedup vs baseline: 1.1103x; 1.1103x over previous
//
#include <hip/hip_runtime.h>
#include <math.h>

// ---------------- dims ----------------
#define B_    4
#define N_    512
#define D_    256
#define H_    8
#define DH_   32
#define M_    110
#define MP_   112           // padded M (pads are exact zeros)
#define FF_   1024
#define HID_  256
#define ROWS_ 2048          // B*N
#define CHUNK 32
#define NCH   16            // N_/CHUNK

// ---------------- ws layout (float offsets) ----------------
#define OFF_H      0u
#define OFF_Y      524288u
#define OFF_Q      1048576u
#define OFF_K      1572864u
#define OFF_V      2097152u
#define OFF_O      2621440u
#define OFF_FF     3145728u   // FF hidden; reused as BLa/BLb in LSTM phase
#define OFF_QP     5242880u   // reused as gi (4194304 spans QP+KP) in LSTM phase
#define OFF_KP     7077888u
#define OFF_S      8912896u
#define OFF_MB     9437184u   // LSTM h-mailboxes, 3 layers x [2][512][4][256]
#define OFF_P      10747904u
#define OFF_KSUM   12582912u
#define OFF_PK     12640256u
#define OFF_DIAG   12697600u
#define OFF_KMAX   12713984u  // 256 uints: 8 layers x 32 slots
// END = 12718208 floats = ~48.5 MiB

#define SCALE_X 0.42044820762685725f   // 32^-0.25
#define SCALE_M 0.09534625892455924f   // 110^-0.5

__device__ __forceinline__ float sigmoidf_(float x){ return 1.0f/(1.0f+expf(-x)); }
__device__ __forceinline__ float geluf_(float x){ return 0.5f*x*(1.0f+erff(x*0.70710678118654752f)); }
__device__ __forceinline__ unsigned encf_(float x){ unsigned u=__float_as_uint(x); return (u&0x80000000u)?~u:(u|0x80000000u); }
__device__ __forceinline__ float decf_(unsigned u){ return (u&0x80000000u)?__uint_as_float(u&0x7fffffffu):__uint_as_float(~u); }

typedef unsigned u32x4_ __attribute__((ext_vector_type(4)));

// Coherent 16B poll load (MALL / device scope) — the proven r9 protocol.
__device__ __forceinline__ u32x4_ ld4_far_(const unsigned* p){
  u32x4_ v;
  asm volatile("global_load_dwordx4 %0, %1, off sc0 sc1\n\ts_waitcnt vmcnt(0)"
               : "=v"(v) : "v"(p));
  return v;
}

// ---------------- generic fp32 GEMM (64x64 tile, reg-prefetched): C = act(A@W^T + b1 + b2) + R ----------------
__global__ __launch_bounds__(256) void gemm_k(
    const float* __restrict__ A, const float* __restrict__ W,
    const float* __restrict__ b1, const float* __restrict__ b2,
    const float* __restrict__ R, float* __restrict__ C,
    int M, int N, int K, int act)
{
  __shared__ float As[16][72];
  __shared__ float Ws[16][72];
  const int tid = threadIdx.x;
  const int tx = tid & 15, ty = tid >> 4;
  const int i0 = blockIdx.y * 64, j0 = blockIdx.x * 64;
  const int lr = tid >> 2, lc = (tid & 3) << 2;
  const float* pA = A + (size_t)(i0 + lr) * K + lc;
  const float* pW = W + (size_t)(j0 + lr) * K + lc;
  float acc[4][4] = {};
  float4 a4 = *(const float4*)pA;
  float4 w4 = *(const float4*)pW;
  for (int k0 = 0; k0 < K; k0 += 16) {
    __syncthreads();
    As[lc+0][lr]=a4.x; As[lc+1][lr]=a4.y; As[lc+2][lr]=a4.z; As[lc+3][lr]=a4.w;
    Ws[lc+0][lr]=w4.x; Ws[lc+1][lr]=w4.y; Ws[lc+2][lr]=w4.z; Ws[lc+3][lr]=w4.w;
    float4 a4n = a4, w4n = w4;
    if (k0 + 16 < K) {                 // prefetch next K-tile; latency hides under the FMA block
      a4n = *(const float4*)(pA + k0 + 16);
      w4n = *(const float4*)(pW + k0 + 16);
    }
    __syncthreads();
    #pragma unroll
    for (int kk = 0; kk < 16; kk++) {
      float4 av = *(const float4*)&As[kk][ty*4];
      float4 wv = *(const float4*)&Ws[kk][tx*4];
      acc[0][0] += av.x*wv.x; acc[0][1] += av.x*wv.y; acc[0][2] += av.x*wv.z; acc[0][3] += av.x*wv.w;
      acc[1][0] += av.y*wv.x; acc[1][1] += av.y*wv.y; acc[1][2] += av.y*wv.z; acc[1][3] += av.y*wv.w;
      acc[2][0] += av.z*wv.x; acc[2][1] += av.z*wv.y; acc[2][2] += av.z*wv.z; acc[2][3] += av.z*wv.w;
      acc[3][0] += av.w*wv.x; acc[3][1] += av.w*wv.y; acc[3][2] += av.w*wv.z; acc[3][3] += av.w*wv.w;
    }
    a4 = a4n; w4 = w4n;
  }
  #pragma unroll
  for (int ii = 0; ii < 4; ii++) {
    int gi_ = i0 + ty*4 + ii;
    #pragma unroll
    for (int jj = 0; jj < 4; jj++) {
      int gj = j0 + tx*4 + jj;
      float v = acc[ii][jj];
      if (b1) v += b1[gj];
      if (b2) v += b2[gj];
      if (act) v = geluf_(v);
      if (R) v += R[(size_t)gi_ * N + gj];
      C[(size_t)gi_ * N + gj] = v;
    }
  }
}

// ---------------- wide fp32 GEMM (128x64 tile, reg-prefetched): C = act(A@W^T + b1) ----------------
__global__ __launch_bounds__(256) void gemmw_k(
    const float* __restrict__ A, const float* __restrict__ W,
    const float* __restrict__ b1, float* __restrict__ C,
    int N, int K, int act)
{
  __shared__ float As[16][136];   // [k][row]
  __shared__ float Ws[16][72];    // [k][col]
  const int tid = threadIdx.x;
  const int tx = tid & 15, ty = tid >> 4;          // ty: 8 rows each
  const int i0 = blockIdx.y * 128, j0 = blockIdx.x * 64;
  const int lrA = tid >> 1, lcA = (tid & 1) << 3;  // A: 128 rows x 16 k, 8 floats/thread
  const int lrW = tid & 63, lcW = (tid >> 6) << 2; // W: 64 rows x 16 k, 4 floats/thread
  const float* pA = A + (size_t)(i0 + lrA) * K + lcA;
  const float* pW = W + (size_t)(j0 + lrW) * K + lcW;
  float acc[8][4] = {};
  float4 a0 = *(const float4*)pA;
  float4 a1 = *(const float4*)(pA + 4);
  float4 w0 = *(const float4*)pW;
  for (int k0 = 0; k0 < K; k0 += 16) {
    __syncthreads();
    As[lcA+0][lrA]=a0.x; As[lcA+1][lrA]=a0.y; As[lcA+2][lrA]=a0.z; As[lcA+3][lrA]=a0.w;
    As[lcA+4][lrA]=a1.x; As[lcA+5][lrA]=a1.y; As[lcA+6][lrA]=a1.z; As[lcA+7][lrA]=a1.w;
    Ws[lcW+0][lrW]=w0.x; Ws[lcW+1][lrW]=w0.y; Ws[lcW+2][lrW]=w0.z; Ws[lcW+3][lrW]=w0.w;
    float4 a0n = a0, a1n = a1, w0n = w0;
    if (k0 + 16 < K) {
      a0n = *(const float4*)(pA + k0 + 16);
      a1n = *(const float4*)(pA + k0 + 20);
      w0n = *(const float4*)(pW + k0 + 16);
    }
    __syncthreads();
    #pragma unroll
    for (int kk = 0; kk < 16; kk++) {
      float4 av0 = *(const float4*)&As[kk][ty*8];
      float4 av1 = *(const float4*)&As[kk][ty*8+4];
      float4 wv  = *(const float4*)&Ws[kk][tx*4];
      acc[0][0]+=av0.x*wv.x; acc[0][1]+=av0.x*wv.y; acc[0][2]+=av0.x*wv.z; acc[0][3]+=av0.x*wv.w;
      acc[1][0]+=av0.y*wv.x; acc[1][1]+=av0.y*wv.y; acc[1][2]+=av0.y*wv.z; acc[1][3]+=av0.y*wv.w;
      acc[2][0]+=av0.z*wv.x; acc[2][1]+=av0.z*wv.y; acc[2][2]+=av0.z*wv.z; acc[2][3]+=av0.z*wv.w;
      acc[3][0]+=av0.w*wv.x; acc[3][1]+=av0.w*wv.y; acc[3][2]+=av0.w*wv.z; acc[3][3]+=av0.w*wv.w;
      acc[4][0]+=av1.x*wv.x; acc[4][1]+=av1.x*wv.y; acc[4][2]+=av1.x*wv.z; acc[4][3]+=av1.x*wv.w;
      acc[5][0]+=av1.y*wv.x; acc[5][1]+=av1.y*wv.y; acc[5][2]+=av1.y*wv.z; acc[5][3]+=av1.y*wv.w;
      acc[6][0]+=av1.z*wv.x; acc[6][1]+=av1.z*wv.y; acc[6][2]+=av1.z*wv.z; acc[6][3]+=av1.z*wv.w;
      acc[7][0]+=av1.w*wv.x; acc[7][1]+=av1.w*wv.y; acc[7][2]+=av1.w*wv.z; acc[7][3]+=av1.w*wv.w;
    }
    a0 = a0n; a1 = a1n; w0 = w0n;
  }
  #pragma unroll
  for (int ii = 0; ii < 8; ii++) {
    int gi_ = i0 + ty*8 + ii;
    #pragma unroll
    for (int jj = 0; jj < 4; jj++) {
      int gj = j0 + tx*4 + jj;
      float v = acc[ii][jj] + b1[gj];
      if (act) v = geluf_(v);
      C[(size_t)gi_ * N + gj] = v;
    }
  }
}

// ---------------- fused QKV GEMM (64x64, reg-prefetched) ----------------
__global__ __launch_bounds__(256) void gemm3_k(
    const float* __restrict__ A,
    const float* __restrict__ W0, const float* __restrict__ W1, const float* __restrict__ W2,
    const float* __restrict__ c0_, const float* __restrict__ c1_, const float* __restrict__ c2_,
    float* __restrict__ O0, float* __restrict__ O1, float* __restrict__ O2)
{
  const int which = blockIdx.x >> 2;
  const float* W  = which == 0 ? W0 : which == 1 ? W1 : W2;
  const float* bb = which == 0 ? c0_ : which == 1 ? c1_ : c2_;
  float* C        = which == 0 ? O0 : which == 1 ? O1 : O2;
  __shared__ float As[16][72];
  __shared__ float Ws[16][72];
  const int tid = threadIdx.x;
  const int tx = tid & 15, ty = tid >> 4;
  const int i0 = blockIdx.y * 64, j0 = (blockIdx.x & 3) * 64;
  const int lr = tid >> 2, lc = (tid & 3) << 2;
  const float* pA = A + (size_t)(i0 + lr) * 256 + lc;
  const float* pW = W + (size_t)(j0 + lr) * 256 + lc;
  float acc[4][4] = {};
  float4 a4 = *(const float4*)pA;
  float4 w4 = *(const float4*)pW;
  for (int k0 = 0; k0 < 256; k0 += 16) {
    __syncthreads();
    As[lc+0][lr]=a4.x; As[lc+1][lr]=a4.y; As[lc+2][lr]=a4.z; As[lc+3][lr]=a4.w;
    Ws[lc+0][lr]=w4.x; Ws[lc+1][lr]=w4.y; Ws[lc+2][lr]=w4.z; Ws[lc+3][lr]=w4.w;
    float4 a4n = a4, w4n = w4;
    if (k0 + 16 < 256) {
      a4n = *(const float4*)(pA + k0 + 16);
      w4n = *(const float4*)(pW + k0 + 16);
    }
    __syncthreads();
    #pragma unroll
    for (int kk = 0; kk < 16; kk++) {
      float4 av = *(const float4*)&As[kk][ty*4];
      float4 wv = *(const float4*)&Ws[kk][tx*4];
      acc[0][0] += av.x*wv.x; acc[0][1] += av.x*wv.y; acc[0][2] += av.x*wv.z; acc[0][3] += av.x*wv.w;
      acc[1][0] += av.y*wv.x; acc[1][1] += av.y*wv.y; acc[1][2] += av.y*wv.z; acc[1][3] += av.y*wv.w;
      acc[2][0] += av.z*wv.x; acc[2][1] += av.z*wv.y; acc[2][2] += av.z*wv.z; acc[2][3] += av.z*wv.w;
      acc[3][0] += av.w*wv.x; acc[3][1] += av.w*wv.y; acc[3][2] += av.w*wv.z; acc[3][3] += av.w*wv.w;
    }
    a4 = a4n; w4 = w4n;
  }
  #pragma unroll
  for (int ii = 0; ii < 4; ii++) {
    int gi_ = i0 + ty*4 + ii;
    #pragma unroll
    for (int jj = 0; jj < 4; jj++) {
      int gj = j0 + tx*4 + jj;
      C[(size_t)gi_ * 256 + gj] = acc[ii][jj] + bb[gj];
    }
  }
}

// ---------------- fused dual-dir LSTM input GEMM (wide 128x64, reg-prefetched) ----------------
__global__ __launch_bounds__(256) void gemmgi_k(
    const float* __restrict__ A, const float* __restrict__ W, const float* __restrict__ bvec,
    float* __restrict__ C, int K, int wGap, int bGap)
{
  const int dir = blockIdx.x >> 4;
  const float* Wd = W + (size_t)dir * wGap;
  const float* b1 = bvec + (size_t)dir * bGap;
  const float* b2 = b1 + 1024;
  float* Cd = C + (size_t)dir * 2097152;
  __shared__ float As[16][136];
  __shared__ float Ws[16][72];
  const int tid = threadIdx.x;
  const int tx = tid & 15, ty = tid >> 4;
  const int i0 = blockIdx.y * 128, j0 = (blockIdx.x & 15) * 64;
  const int lrA = tid >> 1, lcA = (tid & 1) << 3;
  const int lrW = tid & 63, lcW = (tid >> 6) << 2;
  const float* pA = A + (size_t)(i0 + lrA) * K + lcA;
  const float* pW = Wd + (size_t)(j0 + lrW) * K + lcW;
  float acc[8][4] = {};
  float4 a0 = *(const float4*)pA;
  float4 a1 = *(const float4*)(pA + 4);
  float4 w0 = *(const float4*)pW;
  for (int k0 = 0; k0 < K; k0 += 16) {
    __syncthreads();
    As[lcA+0][lrA]=a0.x; As[lcA+1][lrA]=a0.y; As[lcA+2][lrA]=a0.z; As[lcA+3][lrA]=a0.w;
    As[lcA+4][lrA]=a1.x; As[lcA+5][lrA]=a1.y; As[lcA+6][lrA]=a1.z; As[lcA+7][lrA]=a1.w;
    Ws[lcW+0][lrW]=w0.x; Ws[lcW+1][lrW]=w0.y; Ws[lcW+2][lrW]=w0.z; Ws[lcW+3][lrW]=w0.w;
    float4 a0n = a0, a1n = a1, w0n = w0;
    if (k0 + 16 < K) {
      a0n = *(const float4*)(pA + k0 + 16);
      a1n = *(const float4*)(pA + k0 + 20);
      w0n = *(const float4*)(pW + k0 + 16);
    }
    __syncthreads();
    #pragma unroll
    for (int kk = 0; kk < 16; kk++) {
      float4 av0 = *(const float4*)&As[kk][ty*8];
      float4 av1 = *(const float4*)&As[kk][ty*8+4];
      float4 wv  = *(const float4*)&Ws[kk][tx*4];
      acc[0][0]+=av0.x*wv.x; acc[0][1]+=av0.x*wv.y; acc[0][2]+=av0.x*wv.z; acc[0][3]+=av0.x*wv.w;
      acc[1][0]+=av0.y*wv.x; acc[1][1]+=av0.y*wv.y; acc[1][2]+=av0.y*wv.z; acc[1][3]+=av0.y*wv.w;
      acc[2][0]+=av0.z*wv.x; acc[2][1]+=av0.z*wv.y; acc[2][2]+=av0.z*wv.z; acc[2][3]+=av0.z*wv.w;
      acc[3][0]+=av0.w*wv.x; acc[3][1]+=av0.w*wv.y; acc[3][2]+=av0.w*wv.z; acc[3][3]+=av0.w*wv.w;
      acc[4][0]+=av1.x*wv.x; acc[4][1]+=av1.x*wv.y; acc[4][2]+=av1.x*wv.z; acc[4][3]+=av1.x*wv.w;
      acc[5][0]+=av1.y*wv.x; acc[5][1]+=av1.y*wv.y; acc[5][2]+=av1.y*wv.z; acc[5][3]+=av1.y*wv.w;
      acc[6][0]+=av1.z*wv.x; acc[6][1]+=av1.z*wv.y; acc[6][2]+=av1.z*wv.z; acc[6][3]+=av1.z*wv.w;
      acc[7][0]+=av1.w*wv.x; acc[7][1]+=av1.w*wv.y; acc[7][2]+=av1.w*wv.z; acc[7][3]+=av1.w*wv.w;
    }
    a0 = a0n; a1 = a1n; w0 = w0n;
  }
  #pragma unroll
  for (int ii = 0; ii < 8; ii++) {
    int gi_ = i0 + ty*8 + ii;
    #pragma unroll
    for (int jj = 0; jj < 4; jj++) {
      int gj = j0 + tx*4 + jj;
      Cd[(size_t)gi_ * 1024 + gj] = acc[ii][jj] + b1[gj] + b2[gj];
    }
  }
}

// ---------------- LayerNorm over 256 channels ----------------
__global__ __launch_bounds__(256) void ln_k(const float* __restrict__ x, const float* __restrict__ w,
                                            const float* __restrict__ b, float* __restrict__ y)
{
  const int row = blockIdx.x, t = threadIdx.x;
  float v = x[(size_t)row * 256 + t];
  float s = v;
  #pragma unroll
  for (int o = 32; o >= 1; o >>= 1) s += __shfl_xor(s, o, 64);
  __shared__ float w1_[4], w2_[4];
  const int wid = t >> 6, lane = t & 63;
  if (lane == 0) w1_[wid] = s;
  __syncthreads();
  float mu = (w1_[0] + w1_[1] + w1_[2] + w1_[3]) * (1.0f/256.0f);
  float d = v - mu;
  float s2 = d * d;
  #pragma unroll
  for (int o = 32; o >= 1; o >>= 1) s2 += __shfl_xor(s2, o, 64);
  if (lane == 0) w2_[wid] = s2;
  __syncthreads();
  float var = (w2_[0] + w2_[1] + w2_[2] + w2_[3]) * (1.0f/256.0f);
  y[(size_t)row * 256 + t] = d * (1.0f / sqrtf(var + 1e-5f)) * w[t] + b[t];
}

// ---------------- FAVOR+ features, fused q|k ----------------
__global__ __launch_bounds__(256) void feat_k(const float* __restrict__ q, const float* __restrict__ kk,
                                              const float* __restrict__ proj,
                                              float* __restrict__ qp, float* __restrict__ kpraw,
                                              float* __restrict__ diagb, unsigned* __restrict__ kmax)
{
  const int isq = (blockIdx.x < 4096);
  const int bx = isq ? blockIdx.x : (blockIdx.x - 4096);
  const int wid = threadIdx.x >> 6, lane = threadIdx.x & 63;
  const int p = bx * 4 + wid;
  const int bh = p >> 9, n = p & 511;
  const int b = bh >> 3, h = bh & 7;
  __shared__ float xs[4][32];
  const float* xrow = (isq ? q : kk) + ((size_t)(b * N_ + n)) * D_ + h * DH_;
  if (lane < 32) xs[wid][lane] = xrow[lane] * SCALE_X;
  __syncthreads();
  float diag = 0.f;
  #pragma unroll
  for (int d = 0; d < 32; d++) { float xv = xs[wid][d]; diag += xv * xv; }
  diag *= 0.5f;
  const int m0 = lane, m1 = 64 + lane;
  float dd0 = 0.f, dd1 = -INFINITY;
  #pragma unroll
  for (int d = 0; d < 32; d++) dd0 += xs[wid][d] * proj[m0 * 32 + d];
  if (m1 < M_) {
    float a = 0.f;
    #pragma unroll
    for (int d = 0; d < 32; d++) a += xs[wid][d] * proj[m1 * 32 + d];
    dd1 = a;
  }
  float mx = fmaxf(dd0, dd1);
  #pragma unroll
  for (int o = 32; o >= 1; o >>= 1) mx = fmaxf(mx, __shfl_xor(mx, o, 64));
  if (isq) {
    float* out = qp + (size_t)p * MP_;
    out[m0] = SCALE_M * (expf(dd0 - diag - mx) + 1e-4f);
    if (m1 < M_)        out[m1] = SCALE_M * (expf(dd1 - diag - mx) + 1e-4f);
    else if (m1 < MP_)  out[m1] = 0.f;
  } else {
    float* out = kpraw + (size_t)p * MP_;
    out[m0] = dd0;
    if (m1 < M_) out[m1] = dd1;
    if (lane == 0) { diagb[p] = diag; atomicMax(kmax + bh, encf_(mx)); }
  }
}

// ---------------- chunked linear attention: per-chunk K-state sums (finalize fused) ----------------
__global__ __launch_bounds__(256) void csum_k(const float* __restrict__ kp, const float* __restrict__ v,
                                              const float* __restrict__ diagb, const unsigned* __restrict__ kmax,
                                              float* __restrict__ S, float* __restrict__ ksum)
{
  const int bh = blockIdx.x >> 4, c = blockIdx.x & 15;
  const int b = bh >> 3, h = bh & 7;
  __shared__ float kpc[CHUNK * MP_];
  __shared__ float vc[CHUNK][DH_];
  const float* kpbase = kp + ((size_t)bh * N_ + c * CHUNK) * MP_;
  const float kmx = decf_(kmax[bh]);
  const int r0 = bh * N_ + c * CHUNK;
  for (int f = threadIdx.x; f < CHUNK * MP_; f += 256) {
    int i = f / MP_, m = f - i * MP_;
    float raw = kpbase[f];
    float val = 0.f;
    if (m < M_) val = SCALE_M * (expf(raw - diagb[r0 + i] - kmx) + 1e-4f);
    kpc[f] = val;
  }
  for (int f = threadIdx.x; f < CHUNK * DH_; f += 256) {
    int i = f >> 5, d = f & 31;
    vc[i][d] = v[((size_t)(b * N_ + c * CHUNK + i)) * D_ + h * DH_ + d];
  }
  __syncthreads();
  const int d = threadIdx.x & 31, mg = threadIdx.x >> 5;
  float Sa[14] = {};
  for (int i = 0; i < CHUNK; i++) {
    float vv = vc[i][d];
    #pragma unroll
    for (int j = 0; j < 14; j++) Sa[j] += kpc[i * MP_ + mg * 14 + j] * vv;
  }
  float* Sout = S + (((size_t)blockIdx.x) * MP_ + mg * 14) * DH_ + d;
  #pragma unroll
  for (int j = 0; j < 14; j++) Sout[(size_t)j * DH_] = Sa[j];
  if (threadIdx.x < MP_) {
    float s = 0.f;
    for (int i = 0; i < CHUNK; i++) s += kpc[i * MP_ + threadIdx.x];
    ksum[(size_t)blockIdx.x * MP_ + threadIdx.x] = s;
  }
}

// ---------------- exclusive prefix over chunks ----------------
__global__ __launch_bounds__(256) void cpref_k(const float* __restrict__ S, const float* __restrict__ ksum,
                                               float* __restrict__ P, float* __restrict__ pk)
{
  const int bh = blockIdx.x;
  const int d = threadIdx.x & 31, mg = threadIdx.x >> 5;
  float run[14] = {};
  for (int c = 0; c < NCH; c++) {
    size_t base = (((size_t)(bh * NCH + c)) * MP_ + mg * 14) * DH_ + d;
    #pragma unroll
    for (int j = 0; j < 14; j++) { P[base + (size_t)j * DH_] = run[j]; run[j] += S[base + (size_t)j * DH_]; }
  }
  if (threadIdx.x < MP_) {
    float r = 0.f;
    for (int c = 0; c < NCH; c++) {
      size_t o = (size_t)(bh * NCH + c) * MP_ + threadIdx.x;
      pk[o] = r; r += ksum[o];
    }
  }
}

// ---------------- intra-chunk causal attention + combine (k finalize fused) ----------------
__global__ __launch_bounds__(256, 1) void attn_k(const float* __restrict__ qp, const float* __restrict__ kp,
                                                 const float* __restrict__ v, const float* __restrict__ P,
                                                 const float* __restrict__ pk,
                                                 const float* __restrict__ diagb, const unsigned* __restrict__ kmax,
                                                 float* __restrict__ o)
{
  const int bh = blockIdx.x >> 4, c = blockIdx.x & 15;
  const int b = bh >> 3, h = bh & 7;
  __shared__ float qpc[CHUNK * 113];
  __shared__ float kpc[CHUNK * 113];
  __shared__ float vc[CHUNK][DH_];
  __shared__ float Pl[MP_ * DH_];
  __shared__ float pkl[MP_];
  __shared__ float Al[CHUNK * 33];
  __shared__ float den[CHUNK];
  const int t = threadIdx.x;
  const float* qbase = qp + ((size_t)bh * N_ + c * CHUNK) * MP_;
  const float* kbase = kp + ((size_t)bh * N_ + c * CHUNK) * MP_;
  const float kmx = decf_(kmax[bh]);
  const int r0 = bh * N_ + c * CHUNK;
  for (int f = t; f < CHUNK * MP_; f += 256) {
    int i = f / MP_, m = f - i * MP_;
    qpc[i * 113 + m] = qbase[f];
    float raw = kbase[f];
    float val = 0.f;
    if (m < M_) val = SCALE_M * (expf(raw - diagb[r0 + i] - kmx) + 1e-4f);
    kpc[i * 113 + m] = val;
  }
  for (int f = t; f < CHUNK * DH_; f += 256) {
    int i = f >> 5, d = f & 31;
    vc[i][d] = v[((size_t)(b * N_ + c * CHUNK + i)) * D_ + h * DH_ + d];
  }
  for (int f = t; f < MP_ * DH_; f += 256) Pl[f] = P[((size_t)blockIdx.x) * MP_ * DH_ + f];
  if (t < MP_) pkl[t] = pk[(size_t)blockIdx.x * MP_ + t];
  __syncthreads();
  { // causal score tile 2x2 per thread
    const int ti = t >> 4, tj = t & 15;
    float a00 = 0.f, a01 = 0.f, a10 = 0.f, a11 = 0.f;
    for (int m = 0; m < MP_; m++) {
      float q0 = qpc[(ti*2+0)*113 + m], q1 = qpc[(ti*2+1)*113 + m];
      float k0 = kpc[(tj*2+0)*113 + m], k1 = kpc[(tj*2+1)*113 + m];
      a00 += q0*k0; a01 += q0*k1; a10 += q1*k0; a11 += q1*k1;
    }
    const int i0_ = ti*2, j0_ = tj*2;
    Al[(i0_  )*33 + j0_  ] = (j0_   <= i0_  ) ? a00 : 0.f;
    Al[(i0_  )*33 + j0_+1] = (j0_+1 <= i0_  ) ? a01 : 0.f;
    Al[(i0_+1)*33 + j0_  ] = (j0_   <= i0_+1) ? a10 : 0.f;
    Al[(i0_+1)*33 + j0_+1] = (j0_+1 <= i0_+1) ? a11 : 0.f;
  }
  __syncthreads();
  if (t < CHUNK) {
    const int i = t; float s = 0.f;
    for (int m = 0; m < MP_; m++) s += qpc[i*113 + m] * pkl[m];
    for (int j = 0; j <= i; j++) s += Al[i*33 + j];
    den[i] = 1.0f / (s + 1e-6f);
  }
  __syncthreads();
  {
    const int d = t & 31, ig = t >> 5;
    float Pd[MP_];
    #pragma unroll
    for (int m = 0; m < MP_; m++) Pd[m] = Pl[m * DH_ + d];
    float vd[CHUNK];
    #pragma unroll
    for (int j = 0; j < CHUNK; j++) vd[j] = vc[j][d];
    for (int r = 0; r < 4; r++) {
      const int i = ig * 4 + r;
      float acc = 0.f;
      #pragma unroll
      for (int m = 0; m < MP_; m++) acc += qpc[i*113 + m] * Pd[m];
      #pragma unroll
      for (int j = 0; j < CHUNK; j++) acc += Al[i*33 + j] * vd[j];
      o[((size_t)(b * N_ + c * CHUNK + i)) * D_ + h * DH_ + d] = acc * den[i];
    }
  }
}

// ---------------- BiLSTM recurrence: 32 worker blocks (16/dir) — r9 proven protocol (frozen) ----------------
__global__ __launch_bounds__(256, 1) void rec_k(
    const float* __restrict__ gi, const float* __restrict__ whh,
    float* __restrict__ hs, float* __restrict__ hx)
{
  const int bid = blockIdx.x;
  if ((bid & 7) > 1) return;
  const int dir = bid & 7;
  const int s = bid >> 3;
  if (s >= 16) return;
  const int t = threadIdx.x;

  __shared__ __align__(16) float h_sh[4][256];   // [b][k]
  __shared__ __align__(16) float red[64 * 33];   // [rho][b*8+kq]

  __builtin_amdgcn_fence(__ATOMIC_ACQUIRE, "agent");

  const float* giD = gi + (size_t)dir * 2097152;
  const float* whD = whh + (size_t)dir * 262144;
  float* hxD = hx + (size_t)dir * 524288;        // [512][4][256]

  const int rg = t & 31, kq = t >> 5;
  float4 w4[2][8];
  #pragma unroll
  for (int rr = 0; rr < 2; rr++) {
    const int rho = rg * 2 + rr;
    const int grow = (rho >> 4) * 256 + s * 16 + (rho & 15);   // gate-major global row
    const float4* src = (const float4*)(whD + (size_t)grow * 256 + kq * 32);
    #pragma unroll
    for (int q = 0; q < 8; q++) w4[rr][q] = src[q];
  }

  const int j = t & 15, bb = t >> 4;
  const float* pgi0 = giD + (size_t)bb * 524288 + (size_t)(s * 16 + j);

  ((float4*)h_sh)[t] = make_float4(0.f, 0.f, 0.f, 0.f);
  float c0 = 0.f;
  __syncthreads();

  int n = dir ? 511 : 0;
  float gnext[4];
  if (t < 64) {
    #pragma unroll
    for (int g = 0; g < 4; g++) gnext[g] = pgi0[(size_t)n * 1024 + g * 256];
  }

  for (int step = 0; step < 512; step++) {
    const int n2 = dir ? (510 - step) : (step + 1);
    float gcur[4];
    if (t < 64) {
      #pragma unroll
      for (int g = 0; g < 4; g++) gcur[g] = gnext[g];
      if (step < 511) {
        #pragma unroll
        for (int g = 0; g < 4; g++) gnext[g] = pgi0[(size_t)n2 * 1024 + g * 256];
      }
    }

    float acc[2][4] = {};
    #pragma unroll
    for (int q = 0; q < 8; q++) {
      float4 h0 = *(const float4*)&h_sh[0][kq * 32 + q * 4];
      float4 h1 = *(const float4*)&h_sh[1][kq * 32 + q * 4];
      float4 h2 = *(const float4*)&h_sh[2][kq * 32 + q * 4];
      float4 h3 = *(const float4*)&h_sh[3][kq * 32 + q * 4];
      #pragma unroll
      for (int rr = 0; rr < 2; rr++) {
        float4 w = w4[rr][q];
        acc[rr][0] += w.x*h0.x + w.y*h0.y + w.z*h0.z + w.w*h0.w;
        acc[rr][1] += w.x*h1.x + w.y*h1.y + w.z*h1.z + w.w*h1.w;
        acc[rr][2] += w.x*h2.x + w.y*h2.y + w.z*h2.z + w.w*h2.w;
        acc[rr][3] += w.x*h3.x + w.y*h3.y + w.z*h3.z + w.w*h3.w;
      }
    }
    #pragma unroll
    for (int rr = 0; rr < 2; rr++)
      #pragma unroll
      for (int b = 0; b < 4; b++)
        red[(rg * 2 + rr) * 33 + b * 8 + kq] = acc[rr][b];
    __syncthreads();                                     // [A]

    if (t < 64) {
      float pre[4];
      #pragma unroll
      for (int g = 0; g < 4; g++) {
        const float* rp = &red[(g * 16 + j) * 33 + bb * 8];
        float sum = gcur[g];
        #pragma unroll
        for (int q = 0; q < 8; q++) sum += rp[q];
        pre[g] = sum;
      }
      c0 = sigmoidf_(pre[1]) * c0 + sigmoidf_(pre[0]) * tanhf(pre[2]);
      const float hv = sigmoidf_(pre[3]) * tanhf(c0);
      if (step < 511) {
        __hip_atomic_store(hxD + (size_t)step * 1024 + bb * 256 + s * 16 + j, hv,
                           __ATOMIC_RELAXED, __HIP_MEMORY_SCOPE_AGENT);
      }
      hs[(size_t)(bb * 512 + n) * 512 + dir * 256 + s * 16 + j] = hv;
    }

    if (step < 511) {
      const unsigned* pp = (const unsigned*)(hxD + (size_t)step * 1024) + t * 4;
      u32x4_ v = ld4_far_(pp);
      while (v.x == 0xFFFFFFFFu || v.y == 0xFFFFFFFFu ||
             v.z == 0xFFFFFFFFu || v.w == 0xFFFFFFFFu) {
        v = ld4_far_(pp);
      }
      float4 hv4;
      hv4.x = __uint_as_float(v.x); hv4.y = __uint_as_float(v.y);
      hv4.z = __uint_as_float(v.z); hv4.w = __uint_as_float(v.w);
      ((float4*)h_sh)[t] = hv4;
      __syncthreads();                                   // [C]
    }
    n = n2;
  }
}

// ---------------- final head ----------------
__global__ __launch_bounds__(256) void fc_k(const float* __restrict__ hs, const float* __restrict__ fw,
                                            const float* __restrict__ fb, float* __restrict__ out)
{
  const int t = threadIdx.x;
  float p[4] = {};
  for (int j = t; j < 512; j += 256) {
    const float w = fw[j];
    #pragma unroll
    for (int b = 0; b < 4; b++) p[b] += hs[(size_t)(b * 512 + 511) * 512 + j] * w;
  }
  #pragma unroll
  for (int b = 0; b < 4; b++)
    #pragma unroll
    for (int o = 32; o >= 1; o >>= 1) p[b] += __shfl_xor(p[b], o, 64);
  __shared__ float r4[4][4];
  const int wid = t >> 6, lane = t & 63;
  if (lane == 0) {
    #pragma unroll
    for (int b = 0; b < 4; b++) r4[b][wid] = p[b];
  }
  __syncthreads();
  if (t == 0) {
    #pragma unroll
    for (int b = 0; b < 4; b++) out[b] = r4[b][0] + r4[b][1] + r4[b][2] + r4[b][3] + fb[0];
  }
}

// ---------------- host ----------------
extern "C" void kernel_launch(void* const* d_in, const int* in_sizes, int n_in,
                              void* d_out, int out_size, void* d_ws, size_t ws_size,
                              hipStream_t stream) {
  (void)in_sizes; (void)n_in; (void)out_size; (void)ws_size;
  const float* x     = (const float*)d_in[0];
  const float* Win_w = (const float*)d_in[1];
  const float* Win_b = (const float*)d_in[2];
  const float* ln1w  = (const float*)d_in[3];
  const float* ln1b  = (const float*)d_in[4];
  const float* Wq    = (const float*)d_in[5];
  const float* bq    = (const float*)d_in[6];
  const float* Wk    = (const float*)d_in[7];
  const float* bk    = (const float*)d_in[8];
  const float* Wv    = (const float*)d_in[9];
  const float* bv    = (const float*)d_in[10];
  const float* Wo    = (const float*)d_in[11];
  const float* bo    = (const float*)d_in[12];
  const float* proj  = (const float*)d_in[13];
  const float* ln2w  = (const float*)d_in[14];
  const float* ln2b  = (const float*)d_in[15];
  const float* Wff1  = (const float*)d_in[16];
  const float* bff1  = (const float*)d_in[17];
  const float* Wff2  = (const float*)d_in[18];
  const float* bff2  = (const float*)d_in[19];
  const float* Wih0  = (const float*)d_in[20];
  const float* Whh0  = (const float*)d_in[21];
  const float* b0    = (const float*)d_in[22];
  const float* Wih12 = (const float*)d_in[23];
  const float* Whh12 = (const float*)d_in[24];
  const float* b12   = (const float*)d_in[25];
  const float* fcw   = (const float*)d_in[26];
  const float* fcb   = (const float*)d_in[27];

  float* ws = (float*)d_ws;
  float* H   = ws + OFF_H;
  float* Y   = ws + OFF_Y;
  float* Q   = ws + OFF_Q;
  float* Kb  = ws + OFF_K;
  float* V   = ws + OFF_V;
  float* O   = ws + OFF_O;
  float* FFb = ws + OFF_FF;
  float* QP  = ws + OFF_QP;
  float* KP  = ws + OFF_KP;
  float* S   = ws + OFF_S;
  float* P   = ws + OFF_P;
  float* KS  = ws + OFF_KSUM;
  float* PK  = ws + OFF_PK;
  float* DG  = ws + OFF_DIAG;
  unsigned* KMAX = (unsigned*)(ws + OFF_KMAX);   // 8 layers x 32 slots
  float* GI  = ws + OFF_QP;
  float* MA  = ws + OFF_MB;
  float* BLa = ws + OFF_FF;
  float* BLb = ws + OFF_FF + 1048576;

  const dim3 blk(256);
  const dim3 g256(4, 32);              // 64x64 tiles, N=256
  const dim3 g768(12, 32);             // fused QKV
  const dim3 gw1024(16, 16);           // wide 128x64, N=1024 (FF1)
  const dim3 gw2048(32, 16);           // wide 128x64, dual-dir gi

  // zero all 8 layers' kmax slots once (was 8 per-layer memsets)
  (void)hipMemsetAsync(KMAX, 0, 256 * sizeof(unsigned), stream);

  // input projection
  gemm_k<<<g256, blk, 0, stream>>>(x, Win_w, Win_b, nullptr, nullptr, H, ROWS_, 256, 128, 0);

  for (int l = 0; l < 8; l++) {
    const float* prj = proj + (size_t)l * 3520;
    unsigned* kmx = KMAX + l * 32;
    ln_k<<<ROWS_, blk, 0, stream>>>(H, ln1w + l*256, ln1b + l*256, Y);
    gemm3_k<<<g768, blk, 0, stream>>>(Y, Wq + (size_t)l*65536, Wk + (size_t)l*65536, Wv + (size_t)l*65536,
                                      bq + l*256, bk + l*256, bv + l*256, Q, Kb, V);
    feat_k<<<8192, blk, 0, stream>>>(Q, Kb, prj, QP, KP, DG, kmx);
    csum_k<<<512, blk, 0, stream>>>(KP, V, DG, kmx, S, KS);
    cpref_k<<<32, blk, 0, stream>>>(S, KS, P, PK);
    attn_k<<<512, blk, 0, stream>>>(QP, KP, V, P, PK, DG, kmx, O);
    gemm_k<<<g256, blk, 0, stream>>>(O, Wo + (size_t)l*65536, bo + l*256, nullptr, H, H, ROWS_, 256, 256, 0);
    ln_k<<<ROWS_, blk, 0, stream>>>(H, ln2w + l*256, ln2b + l*256, Y);
    gemmw_k<<<gw1024, blk, 0, stream>>>(Y, Wff1 + (size_t)l*262144, bff1 + l*1024, FFb, 1024, 256, 1);
    gemm_k<<<g256, blk, 0, stream>>>(FFb, Wff2 + (size_t)l*262144, bff2 + l*256, nullptr, H, H, ROWS_, 256, 1024, 0);
  }

  // sentinel-fill all three mailbox regions once
  (void)hipMemsetAsync(MA, 0xFF, 3145728u * sizeof(float), stream);

  // ---- BiLSTM layer 0 (input H, K=256) ----
  gemmgi_k<<<gw2048, blk, 0, stream>>>(H, Wih0, b0, GI, 256, 262144, 2048);
  rec_k<<<128, blk, 0, stream>>>(GI, Whh0, BLa, MA);

  // ---- layer 1 (input BLa, K=512) ----
  gemmgi_k<<<gw2048, blk, 0, stream>>>(BLa, Wih12, b12, GI, 512, 524288, 2048);
  rec_k<<<128, blk, 0, stream>>>(GI, Whh12, BLb, MA + 1048576);

  // ---- layer 2 (input BLb, K=512) ----
  gemmgi_k<<<gw2048, blk, 0, stream>>>(BLb, Wih12 + 1048576, b12 + 4096, GI, 512, 524288, 2048);
  rec_k<<<128, blk, 0, stream>>>(GI, Whh12 + 524288, BLa, MA + 2097152);

  fc_k<<<1, blk, 0, stream>>>(BLa, fcw, fcb, (float*)d_out);
}